// Round 11
// baseline (945.333 us; speedup 1.0000x reference)
//
#include <hip/hip_runtime.h>
#include <hip/hip_bf16.h>
#include <cstdint>
#include <cstddef>

// Problem dims (fixed by reference)
#define T_STEPS 500
#define BATCH   128
#define FDIM    128
#define HDIM    512
#define ODIM    32
#define M_ROWS  (T_STEPS * BATCH)   // 64000
#define ZOFF    (512u << 11)        // zero-row byte offset, fp32 WrecT (2 KB rows)
#define ZOFFB   (512u << 10)        // zero-row byte offset, bf16 WrecTb (1 KB rows)

typedef __attribute__((ext_vector_type(8))) __bf16 bf16x8;
typedef __attribute__((ext_vector_type(4))) float  f32x4;

__device__ __forceinline__ float bfbits2f(unsigned short u) {
    union { unsigned int i; float f; } c; c.i = ((unsigned int)u) << 16; return c.f;
}
__device__ __forceinline__ float asf(unsigned int u) {
    union { unsigned int i; float f; } c; c.i = u; return c.f;
}

// ---------------------------------------------------------------------------
// Dtype detect: flag=1 -> fp32 inputs (measured live on this harness), 0 -> bf16.
// ---------------------------------------------------------------------------
__global__ void detect_kernel(const unsigned short* __restrict__ xw, int* __restrict__ flag) {
    __shared__ int cnt;
    if (threadIdx.x == 0) cnt = 0;
    __syncthreads();
    unsigned short w = xw[threadIdx.x * 2];
    int e = (w >> 7) & 0xFF;
    if (e >= 170) atomicAdd(&cnt, 1);
    __syncthreads();
    if (threadIdx.x == 0) *flag = (cnt >= 8) ? 1 : 0;
}

// ---------------------------------------------------------------------------
// Prep. flag==1 (fp32): WrecT fp32 transpose (+zero row).
//       flag==0 (bf16): WrecTb raw-bit transpose (+zero row).
// WoutT (fp32 [h][o]) and bout32 built either way. (Validated R8/R10.)
// ---------------------------------------------------------------------------
__global__ void prep_kernel(const void* __restrict__ Wrec,
                            const void* __restrict__ Wout,
                            const void* __restrict__ bout,
                            const int* __restrict__ flag,
                            float* __restrict__ WrecT,
                            unsigned short* __restrict__ WrecTb,
                            float* __restrict__ WoutT,
                            float* __restrict__ bout32) {
    const int fp32 = *flag;
    int idx = blockIdx.x * blockDim.x + threadIdx.x;
    if (fp32) {
        if (idx < HDIM * HDIM) {
            int h = idx / HDIM, hp = idx % HDIM;
            WrecT[hp * HDIM + h] = ((const float*)Wrec)[idx];
        }
        if (idx < HDIM) WrecT[HDIM * HDIM + idx] = 0.f;
    } else {
        if (idx < HDIM * HDIM) {
            int h = idx / HDIM, hp = idx % HDIM;
            WrecTb[hp * HDIM + h] = ((const unsigned short*)Wrec)[idx];
        }
        if (idx < HDIM) WrecTb[HDIM * HDIM + idx] = 0;
    }
    if (idx < ODIM * HDIM) {
        int o = idx / HDIM, h = idx % HDIM;
        WoutT[h * ODIM + o] = fp32 ? ((const float*)Wout)[idx]
                                   : bfbits2f(((const unsigned short*)Wout)[idx]);
    }
    if (idx < ODIM)
        bout32[idx] = fp32 ? ((const float*)bout)[idx]
                           : bfbits2f(((const unsigned short*)bout)[idx]);
}

// ---------------------------------------------------------------------------
// i_in GEMM, MFMA path (flag==0 / bf16 only — dead on this harness).
// ---------------------------------------------------------------------------
__global__ __launch_bounds__(256) void iin_gemm_mfma(const __hip_bfloat16* __restrict__ x,
                                                     const __hip_bfloat16* __restrict__ Win,
                                                     const int* __restrict__ flag,
                                                     float* __restrict__ iin) {
    if (*flag != 0) return;
    const int mt   = blockIdx.x;
    const int nt   = blockIdx.y & 7;
    const int wave = threadIdx.x >> 6;
    const int lane = threadIdx.x & 63;
    const int l15  = lane & 15;
    const int quad = lane >> 4;
    const int m_base = mt * 64 + wave * 16;
    const int n_base = nt * 64;

    const __bf16* xb = reinterpret_cast<const __bf16*>(x);
    const __bf16* wb = reinterpret_cast<const __bf16*>(Win);

    f32x4 acc[4] = {{0.f,0.f,0.f,0.f},{0.f,0.f,0.f,0.f},{0.f,0.f,0.f,0.f},{0.f,0.f,0.f,0.f}};

#pragma unroll
    for (int kk = 0; kk < 4; ++kk) {
        const int k0 = kk * 32 + quad * 8;
        bf16x8 a = *reinterpret_cast<const bf16x8*>(xb + (size_t)(m_base + l15) * FDIM + k0);
#pragma unroll
        for (int nb = 0; nb < 4; ++nb) {
            bf16x8 bf = *reinterpret_cast<const bf16x8*>(wb + (size_t)(n_base + nb * 16 + l15) * FDIM + k0);
            acc[nb] = __builtin_amdgcn_mfma_f32_16x16x32_bf16(a, bf, acc[nb], 0, 0, 0);
        }
    }

#pragma unroll
    for (int nb = 0; nb < 4; ++nb)
#pragma unroll
        for (int r = 0; r < 4; ++r)
            iin[(size_t)(m_base + quad * 4 + r) * HDIM + n_base + nb * 16 + l15] = acc[nb][r];
}

// ---------------------------------------------------------------------------
// i_in GEMM v4, fp32 VALU (flag==1, LIVE). Standard LDS-tiled 64x64 with
// 4x4 register micro-tiles. Both source tiles are contiguous 32 KB rows of
// x / Win -> perfectly coalesced float4 staging. Per k4: 8 ds_read_b128 +
// 64 FMA. Per-output k-accumulation strictly ascending (same numerics class
// as validated v2/v3). Grid (1000, 8).
// ---------------------------------------------------------------------------
#define GPAD 132   // LDS row stride in floats (128 + 4, keeps 16B alignment)
__global__ __launch_bounds__(256) void iin_gemm_valu(const float* __restrict__ x,
                                                     const float* __restrict__ Win,
                                                     const int* __restrict__ flag,
                                                     float* __restrict__ iin) {
    if (*flag != 1) return;
    const int tid = threadIdx.x;
    const int m0  = blockIdx.x * 64;
    const int n0  = blockIdx.y * 64;

    __shared__ float xs[64][GPAD];   // 33.8 KB
    __shared__ float wt[64][GPAD];   // 33.8 KB

    {   // stage x tile (rows m0..m0+63 contiguous) and W tile (rows n0..n0+63)
        const float4* xsrc = (const float4*)(x   + (size_t)m0 * FDIM);
        const float4* wsrc = (const float4*)(Win + (size_t)n0 * FDIM);
#pragma unroll
        for (int it = 0; it < 8; ++it) {
            int f4 = tid + it * 256;          // 0..2047
            int r  = f4 >> 5;                 // row 0..63
            int c4 = f4 & 31;                 // float4-col 0..31
            *(float4*)&xs[r][c4 * 4] = xsrc[f4];
            *(float4*)&wt[r][c4 * 4] = wsrc[f4];
        }
    }
    __syncthreads();

    const int ty = tid >> 4;    // m group 0..15
    const int tx = tid & 15;    // n group 0..15

    float acc[4][4];
#pragma unroll
    for (int i = 0; i < 4; ++i)
#pragma unroll
        for (int j = 0; j < 4; ++j) acc[i][j] = 0.f;

    for (int k4 = 0; k4 < FDIM / 4; ++k4) {
        float4 a[4], bw[4];
#pragma unroll
        for (int i = 0; i < 4; ++i) a[i]  = *(const float4*)&xs[ty * 4 + i][k4 * 4];
#pragma unroll
        for (int j = 0; j < 4; ++j) bw[j] = *(const float4*)&wt[tx * 4 + j][k4 * 4];
#pragma unroll
        for (int i = 0; i < 4; ++i)
#pragma unroll
            for (int j = 0; j < 4; ++j) {
                float s = acc[i][j];
                s += a[i].x * bw[j].x;
                s += a[i].y * bw[j].y;
                s += a[i].z * bw[j].z;
                s += a[i].w * bw[j].w;
                acc[i][j] = s;
            }
    }

#pragma unroll
    for (int i = 0; i < 4; ++i) {
        float4 o = {acc[i][0], acc[i][1], acc[i][2], acc[i][3]};
        *(float4*)&iin[(size_t)(m0 + ty * 4 + i) * HDIM + n0 + tx * 4] = o;
    }
}

// ---------------------------------------------------------------------------
// Scan (flag==1, LIVE) — R10 skeleton VERBATIM (two __syncthreads; passed
// three rounds replay-stable at 648 µs). Only change: float4 accumulation
// via ext-vector adds (candidate v_pk_add_f32 selection; per-component
// chains unchanged -> bit-identical). DO NOT single-barrier (R8/R9 failed).
// ---------------------------------------------------------------------------
__global__ __launch_bounds__(1024) void scan_f32(const float* __restrict__ iin,
                                                 const float* __restrict__ WrecT,
                                                 const int* __restrict__ flag,
                                                 unsigned long long* __restrict__ masksG) {
    if (*flag != 1) return;
    const int b    = blockIdx.x;
    const int tid  = threadIdx.x;
    const int q    = tid & 127;
    const int p    = tid >> 7;
    const int lane = tid & 63;
    const int wv   = tid >> 6;
    const bool st  = tid < HDIM;
    const int h    = tid;

    __shared__ unsigned long long wmask[8];
    __shared__ f32x4 part[8][128];
    __shared__ alignas(16) unsigned int slA[8][68];
    __shared__ alignas(16) unsigned int slB[8][68];
    unsigned int (*slO)[68] = slA;
    unsigned int (*slN)[68] = slB;

    float v = 0.f, cur = 0.f, a = 0.f;
    int   cnt = 0;
    const char* WQ = (const char*)WrecT + q * 16;

    for (int t = 0; t < T_STEPS; ++t) {
        float ic = 0.f, i_dec = 0.f;
        bool  zk = false;
        unsigned long long m = 0;

        if (st) {
            ic = iin[((size_t)t * BATCH + b) * HDIM + h];
            float s = (0.0f - v) + 0.5f * expf((v - 1.0f) * 2.0f);
            s = s + cur;
            s = s - a;
            float v_dec = v + 0.1f * s;
            i_dec = cur - 0.2f * cur;
            float a_dec = a + 0.002f * (4.0f * v - a);
            zk = (v_dec - 1.0f) > 0.0f;
            m = __ballot(zk);
            if (lane == 0) {
                wmask[wv] = m;
                masksG[((size_t)t * BATCH + b) * 8 + wv] = m;
            }
            v = zk ? 0.0f : v_dec;
            a = zk ? (a_dec + 0.02f) : a_dec;
        }

        f32x4 rs = {0.f, 0.f, 0.f, 0.f};
        {
            const int n  = (cnt + 7 - p) >> 3;
            const int ng = (n + 3) >> 2;
            f32x4 b0[4], b1[4];
            auto ld4 = [&](int g, f32x4* d) {
                uint4 i0 = *(const uint4*)&slO[p][g << 2];
                d[0] = *(const f32x4*)(WQ + i0.x);
                d[1] = *(const f32x4*)(WQ + i0.y);
                d[2] = *(const f32x4*)(WQ + i0.z);
                d[3] = *(const f32x4*)(WQ + i0.w);
            };
            auto acc4 = [&](const f32x4* d) {
#pragma unroll
                for (int u = 0; u < 4; ++u) rs = rs + d[u];   // vector fadd
            };
            int g = 0;
            if (ng > 0) ld4(0, b0);
            while (g + 2 <= ng) {
                ld4(g + 1, b1);
                acc4(b0);
                if (g + 2 < ng) ld4(g + 2, b0);
                acc4(b1);
                g += 2;
            }
            if (g < ng) acc4(b0);
        }
        part[p][q] = rs;

        __syncthreads();

        int total = 0;
#pragma unroll
        for (int w = 0; w < 8; ++w) total += __popcll(wmask[w]);

        if (st) {
            float rec = 0.f;
#pragma unroll
            for (int pp = 0; pp < 8; ++pp)
                rec += ((const float*)&part[pp][h >> 2])[h & 3];
            cur = (i_dec + ic) + rec;
            if (zk) {
                int off = __popcll(m & ((1ull << lane) - 1ull));
#pragma unroll
                for (int w = 0; w < 8; ++w) if (w < wv) off += __popcll(wmask[w]);
                slN[off & 7][off >> 3] = (unsigned int)h << 11;
            }
        } else if (tid < HDIM + 32) {
            int s5 = (tid - HDIM) >> 2;
            int k  = (tid - HDIM) & 3;
            int ne = (total + 7 - s5) >> 3;
            int padc = (4 - (ne & 3)) & 3;
            if (k < padc) slN[s5][ne + k] = ZOFF;
        }
        cnt = total;

        __syncthreads();

        unsigned int (*tp)[68] = slO; slO = slN; slN = tp;
    }
}

// ---------------------------------------------------------------------------
// Scan, bf16-weight path (flag==0 — dead on this harness, kept for safety).
// ---------------------------------------------------------------------------
__global__ __launch_bounds__(1024) void scan_bf16(const float* __restrict__ iin,
                                                  const unsigned short* __restrict__ WrecTb,
                                                  const int* __restrict__ flag,
                                                  unsigned long long* __restrict__ masksG) {
    if (*flag != 0) return;
    const int b    = blockIdx.x;
    const int tid  = threadIdx.x;
    const int q    = tid & 63;
    const int pc   = tid >> 6;
    const int lane = tid & 63;
    const int wv   = tid >> 6;
    const bool st  = tid < HDIM;
    const int h    = tid;

    __shared__ unsigned long long wmask[8];
    __shared__ float4 partA[16][64];
    __shared__ float4 partB[16][64];
    __shared__ alignas(16) unsigned int slA[16][36];
    __shared__ alignas(16) unsigned int slB[16][36];
    unsigned int (*slO)[36] = slA;
    unsigned int (*slN)[36] = slB;

    float v = 0.f, cur = 0.f, a = 0.f;
    int   cnt = 0;
    const char* WQ = (const char*)WrecTb + q * 16;

    for (int t = 0; t < T_STEPS; ++t) {
        float ic = 0.f, i_dec = 0.f; bool zk = false; unsigned long long m = 0;
        if (st) {
            ic = iin[((size_t)t * BATCH + b) * HDIM + h];
            float s = (0.0f - v) + 0.5f * expf((v - 1.0f) * 2.0f);
            s = s + cur;
            s = s - a;
            float v_dec = v + 0.1f * s;
            i_dec = cur - 0.2f * cur;
            float a_dec = a + 0.002f * (4.0f * v - a);
            zk = (v_dec - 1.0f) > 0.0f;
            m = __ballot(zk);
            if (lane == 0) {
                wmask[wv] = m;
                masksG[((size_t)t * BATCH + b) * 8 + wv] = m;
            }
            v = zk ? 0.0f : v_dec;
            a = zk ? (a_dec + 0.02f) : a_dec;
        }

        float rs0=0.f,rs1=0.f,rs2=0.f,rs3=0.f,rs4=0.f,rs5=0.f,rs6=0.f,rs7=0.f;
        {
            const unsigned int* sl = slO[pc];
            const int n  = (cnt + 15 - pc) >> 4;
            const int ng = (n + 3) >> 2;
            uint4 w0[4], w1[4];
            auto ldg = [&](int g, uint4* w) {
                uint4 ix = *(const uint4*)(sl + (g << 2));
                w[0] = *(const uint4*)(WQ + ix.x);
                w[1] = *(const uint4*)(WQ + ix.y);
                w[2] = *(const uint4*)(WQ + ix.z);
                w[3] = *(const uint4*)(WQ + ix.w);
            };
            auto accw = [&](const uint4* w) {
#pragma unroll
                for (int u = 0; u < 4; ++u) {
                    rs0 += asf(w[u].x << 16); rs1 += asf(w[u].x & 0xffff0000u);
                    rs2 += asf(w[u].y << 16); rs3 += asf(w[u].y & 0xffff0000u);
                    rs4 += asf(w[u].z << 16); rs5 += asf(w[u].z & 0xffff0000u);
                    rs6 += asf(w[u].w << 16); rs7 += asf(w[u].w & 0xffff0000u);
                }
            };
            int g = 0;
            if (ng > 0) ldg(0, w0);
            while (g + 2 <= ng) {
                ldg(g + 1, w1);
                accw(w0);
                if (g + 2 < ng) ldg(g + 2, w0);
                accw(w1);
                g += 2;
            }
            if (g < ng) accw(w0);
        }
        partA[pc][q] = (float4){rs0, rs1, rs2, rs3};
        partB[pc][q] = (float4){rs4, rs5, rs6, rs7};

        __syncthreads();

        int total = 0;
#pragma unroll
        for (int w = 0; w < 8; ++w) total += __popcll(wmask[w]);

        if (st) {
            float rec = 0.f;
            const int  qq = h >> 3, jj = h & 3;
            const bool hi = (h & 4) != 0;
#pragma unroll
            for (int pp = 0; pp < 16; ++pp) {
                const float* pa = (const float*)&partA[pp][qq];
                const float* pb = (const float*)&partB[pp][qq];
                rec += hi ? pb[jj] : pa[jj];
            }
            cur = (i_dec + ic) + rec;
            if (zk) {
                int off = __popcll(m & ((1ull << lane) - 1ull));
#pragma unroll
                for (int w = 0; w < 8; ++w) if (w < wv) off += __popcll(wmask[w]);
                slN[off & 15][off >> 4] = (unsigned int)h << 10;
            }
        } else if (tid < HDIM + 64) {
            int s5 = (tid - HDIM) >> 2;
            int k  = (tid - HDIM) & 3;
            int ne = (total + 15 - s5) >> 4;
            int padc = (4 - (ne & 3)) & 3;
            if (k < padc) slN[s5][ne + k] = ZOFFB;
        }
        cnt = total;

        __syncthreads();

        unsigned int (*tp)[36] = slO; slO = slN; slN = tp;
    }
}

// ---------------------------------------------------------------------------
// Readout from spike masks: y[t][b][o] = sum_{h' spiking} WoutT[h'][o] + b[o]
// ---------------------------------------------------------------------------
__global__ __launch_bounds__(256) void y_kernel(const unsigned long long* __restrict__ masks,
                                                const float* __restrict__ WoutT,
                                                const float* __restrict__ bout,
                                                float* __restrict__ y) {
    const int tid = threadIdx.x;
    const int p   = blockIdx.x * 8 + (tid >> 5);   // t*BATCH + b
    const int o   = tid & 31;
    const unsigned long long* mp = masks + (size_t)p * 8;
    float acc = 0.f;
#pragma unroll
    for (int w = 0; w < 8; ++w) {
        unsigned long long m = mp[w];
        const float* Wb = WoutT + (size_t)w * 64 * ODIM + o;
        while (m) {
            int j = __builtin_ctzll(m);
            acc += Wb[j * ODIM];
            m &= m - 1;
        }
    }
    y[(size_t)p * ODIM + o] = acc + bout[o];
}

// ---------------------------------------------------------------------------
// Exponential filter over t: 4096 independent (b,o) chains; chunked prefetch.
// ---------------------------------------------------------------------------
__global__ __launch_bounds__(64) void filter_kernel(const float* __restrict__ y,
                                                    const int* __restrict__ flag,
                                                    void* __restrict__ out) {
    const int p = blockIdx.x * 64 + threadIdx.x;   // b*ODIM + o
    const int fp32o = *flag;
    const float kf = 0.2231435511314f;   // DT*TAU_FILTER_INV
    float c0[10], c1[10];
#pragma unroll
    for (int u = 0; u < 10; ++u) c0[u] = y[(size_t)u * (BATCH * ODIM) + p];
    float o_state = 0.f;
    for (int base = 0; base < T_STEPS; base += 10) {
        if (base + 10 < T_STEPS) {
#pragma unroll
            for (int u = 0; u < 10; ++u)
                c1[u] = y[(size_t)(base + 10 + u) * (BATCH * ODIM) + p];
        }
#pragma unroll
        for (int u = 0; u < 10; ++u) {
            int t = base + u;
            float yt = c0[u];
            o_state = (t == 0) ? yt : (o_state + kf * (yt - o_state));
            size_t oi = (size_t)t * (BATCH * ODIM) + p;
            if (fp32o) ((float*)out)[oi] = o_state;
            else       ((__hip_bfloat16*)out)[oi] = __float2bfloat16(o_state);
        }
#pragma unroll
        for (int u = 0; u < 10; ++u) c0[u] = c1[u];
    }
}

// ---------------------------------------------------------------------------
extern "C" void kernel_launch(void* const* d_in, const int* in_sizes, int n_in,
                              void* d_out, int out_size, void* d_ws, size_t ws_size,
                              hipStream_t stream) {
    // select inputs by unique element count (robust to ordering)
    const void* x = d_in[0]; const void* Win = d_in[1]; const void* Wrec = d_in[2];
    const void* Wout = d_in[3]; const void* bout = d_in[4];
    for (int i = 0; i < n_in; ++i) {
        switch (in_sizes[i]) {
            case 8192000: x    = d_in[i]; break;
            case 65536:   Win  = d_in[i]; break;
            case 262144:  Wrec = d_in[i]; break;
            case 16384:   Wout = d_in[i]; break;
            case 32:      bout = d_in[i]; break;
            default: break;
        }
    }

    // workspace layout (bytes) — WrecTb (bf16) aliases WrecT (fp32) storage
    const size_t OFF_FLAG  = 0;          // 4
    const size_t OFF_BOUT  = 256;        // 128
    const size_t OFF_WOUTT = 512;        // 65536
    const size_t OFF_WRECT = 66048;      // 513*512*4 = 1050624
    const size_t OFF_MASK  = 1378816;    // 500*128*8*8 = 4096000
    const size_t OFF_IIN   = 5474816;    // 64000*512*4 = 131072000
    const size_t OFF_Y     = OFF_IIN;    // y (8.2 MB) aliases iin (dead after scan)
    const size_t REQUIRED  = OFF_IIN + (size_t)M_ROWS * HDIM * 4;  // 136546816
    if (ws_size < REQUIRED) return;  // diagnostic: output stays 0

    char* ws = (char*)d_ws;
    int*            flag   = (int*)(ws + OFF_FLAG);
    float*          bout32 = (float*)(ws + OFF_BOUT);
    float*          WoutT  = (float*)(ws + OFF_WOUTT);
    float*          WrecT  = (float*)(ws + OFF_WRECT);
    unsigned short* WrecTb = (unsigned short*)(ws + OFF_WRECT);
    unsigned long long* masks = (unsigned long long*)(ws + OFF_MASK);
    float*          iin    = (float*)(ws + OFF_IIN);
    float*          y      = (float*)(ws + OFF_Y);

    hipLaunchKernelGGL(detect_kernel, dim3(1), dim3(256), 0, stream,
                       (const unsigned short*)x, flag);
    hipLaunchKernelGGL(prep_kernel, dim3((HDIM * HDIM + 255) / 256), dim3(256), 0, stream,
                       Wrec, Wout, bout, flag, WrecT, WrecTb, WoutT, bout32);
    hipLaunchKernelGGL(iin_gemm_mfma, dim3(M_ROWS / 64, HDIM / 64), dim3(256), 0, stream,
                       (const __hip_bfloat16*)x, (const __hip_bfloat16*)Win, flag, iin);
    hipLaunchKernelGGL(iin_gemm_valu, dim3(M_ROWS / 64, HDIM / 64), dim3(256), 0, stream,
                       (const float*)x, (const float*)Win, flag, iin);
    hipLaunchKernelGGL(scan_f32, dim3(BATCH), dim3(1024), 0, stream,
                       iin, WrecT, flag, masks);
    hipLaunchKernelGGL(scan_bf16, dim3(BATCH), dim3(1024), 0, stream,
                       iin, WrecTb, flag, masks);
    hipLaunchKernelGGL(y_kernel, dim3(M_ROWS / 8), dim3(256), 0, stream,
                       masks, WoutT, bout32, y);
    hipLaunchKernelGGL(filter_kernel, dim3((BATCH * ODIM) / 64), dim3(64), 0, stream,
                       y, flag, d_out);
}